// Round 2
// baseline (74873.730 us; speedup 1.0000x reference)
//
#include <hip/hip_runtime.h>
#include <hip/hip_bf16.h>
#include <stdint.h>

// ---------------------------------------------------------------------------
// BioDecoder: 64-step LSTM decoder w/ attention, rep-penalty, temperature=0.4,
// top-p=0.7, jax.random.categorical (Threefry partitionable). All fp32.
// Association discipline: every dot = strict sequential-k single-acc fma chain
// (matches Eigen/OpenBLAS microkernels); elementwise ops non-contracted.
// ---------------------------------------------------------------------------

#define B_   64
#define H_   1024
#define E_   512
#define DV_  512
#define KV_  49
#define V_   32000
#define T_   64

// ------------------------- Threefry-2x32-20 (JAX) --------------------------
__device__ __forceinline__ uint32_t rotl32(uint32_t x, int r) {
  return (x << r) | (x >> (32 - r));
}
__device__ __forceinline__ void tf2x32(uint32_t k0, uint32_t k1,
                                       uint32_t x0, uint32_t x1,
                                       uint32_t& o0, uint32_t& o1) {
  uint32_t ks0 = k0, ks1 = k1, ks2 = k0 ^ k1 ^ 0x1BD11BDAu;
  x0 += ks0; x1 += ks1;
#define RND_(r) { x0 += x1; x1 = rotl32(x1, r) ^ x0; }
  RND_(13) RND_(15) RND_(26) RND_(6)  x0 += ks1; x1 += ks2 + 1u;
  RND_(17) RND_(29) RND_(16) RND_(24) x0 += ks2; x1 += ks0 + 2u;
  RND_(13) RND_(15) RND_(26) RND_(6)  x0 += ks0; x1 += ks1 + 3u;
  RND_(17) RND_(29) RND_(16) RND_(24) x0 += ks1; x1 += ks2 + 4u;
  RND_(13) RND_(15) RND_(26) RND_(6)  x0 += ks2; x1 += ks0 + 5u;
#undef RND_
  o0 = x0; o1 = x1;
}

__device__ __forceinline__ unsigned key_of(float f) {
  unsigned u = __float_as_uint(f);
  return (u & 0x80000000u) ? ~u : (u | 0x80000000u);
}
__device__ __forceinline__ float sigf(float x) { return 1.0f / (1.0f + expf(-x)); }

// ------------------------- sequential-k GEMM -------------------------------
// out[m][n] = sum_k A[m][k]*W[n][k], k ascending, one fma chain per output.
__global__ __launch_bounds__(256)
void gemm_seq(const float* __restrict__ A, int lda,
              const float* __restrict__ W, int ldw,
              float* __restrict__ out, int ldo, int K) {
  __shared__ __align__(16) float As[64][36];
  __shared__ __align__(16) float Ws[64][34];
  int tid = threadIdx.x;
  int tc = tid & 15, tr = tid >> 4;
  int n0 = blockIdx.x * 64, m0 = blockIdx.y * 64;
  float acc[4][4] = {};
  for (int kc = 0; kc < K; kc += 32) {
#pragma unroll
    for (int l = tid; l < 2048; l += 256) {
      int r = l >> 5, c = l & 31;
      As[r][c] = A[(long long)(m0 + r) * lda + kc + c];
      Ws[r][c] = W[(long long)(n0 + r) * ldw + kc + c];
    }
    __syncthreads();
#pragma unroll
    for (int kk = 0; kk < 32; kk += 2) {
      float2 a2[4], w2[4];
#pragma unroll
      for (int i = 0; i < 4; i++) a2[i] = *(const float2*)&As[tr * 4 + i][kk];
#pragma unroll
      for (int j = 0; j < 4; j++) w2[j] = *(const float2*)&Ws[tc * 4 + j][kk];
#pragma unroll
      for (int i = 0; i < 4; i++)
#pragma unroll
        for (int j = 0; j < 4; j++) {
          acc[i][j] = fmaf(a2[i].x, w2[j].x, acc[i][j]);   // k
          acc[i][j] = fmaf(a2[i].y, w2[j].y, acc[i][j]);   // k+1
        }
    }
    __syncthreads();
  }
#pragma unroll
  for (int i = 0; i < 4; i++)
#pragma unroll
    for (int j = 0; j < 4; j++)
      out[(long long)(m0 + tr * 4 + i) * ldo + n0 + tc * 4 + j] = acc[i][j];
}

// ------------------------- LayerNorm for vp --------------------------------
__global__ __launch_bounds__(256)
void ln_vp(float* __restrict__ vp, const float* __restrict__ bv,
           const float* __restrict__ g, const float* __restrict__ bt) {
  int row = blockIdx.x, tid = threadIdx.x;
  __shared__ float buf[H_];
  __shared__ float red[256];
  float* p = vp + (long long)row * H_;
  for (int h = tid; h < H_; h += 256) buf[h] = __fadd_rn(p[h], bv[h]);
  __syncthreads();
  float s = 0;
  for (int h = tid; h < H_; h += 256) s += buf[h];
  red[tid] = s; __syncthreads();
  for (int off = 128; off > 0; off >>= 1) { if (tid < off) red[tid] += red[tid + off]; __syncthreads(); }
  float mu = red[0] / (float)H_;
  __syncthreads();
  float vs = 0;
  for (int h = tid; h < H_; h += 256) { float d = buf[h] - mu; vs += d * d; }
  red[tid] = vs; __syncthreads();
  for (int off = 128; off > 0; off >>= 1) { if (tid < off) red[tid] += red[tid + off]; __syncthreads(); }
  float var = red[0] / (float)H_;
  float sq = sqrtf(var + 1e-5f);
  for (int h = tid; h < H_; h += 256) {
    float nrm = __fdiv_rn(__fsub_rn(buf[h], mu), sq);
    p[h] = __fadd_rn(__fmul_rn(nrm, g[h]), bt[h]);
  }
}

// ------------------------- LSTM cell ---------------------------------------
// z = ((dx + dh) + bih) + bhh  (left-assoc, matches ref); gate order i,f,g,o.
__global__ __launch_bounds__(256)
void lstm_cell2(const float* __restrict__ dx, const float* __restrict__ dh,
                const float* __restrict__ bih, const float* __restrict__ bhh,
                float* __restrict__ c,
                float* __restrict__ hA, int ldA, float* __restrict__ hB, int ldB) {
  int idx = blockIdx.x * 256 + threadIdx.x;      // 64*1024
  int b = idx >> 10, h = idx & 1023;
  float z[4];
#pragma unroll
  for (int g = 0; g < 4; g++) {
    int j = g * 1024 + h;
    float s = __fadd_rn(dx[b * 4096 + j], dh[b * 4096 + j]);
    s = __fadd_rn(s, bih[j]);
    s = __fadd_rn(s, bhh[j]);
    z[g] = s;
  }
  float fc = __fmul_rn(sigf(z[1]), c[idx]);
  float ig = __fmul_rn(sigf(z[0]), tanhf(z[2]));
  float cn = __fadd_rn(fc, ig);
  float hn = __fmul_rn(sigf(z[3]), tanhf(cn));
  c[idx] = cn;
  hA[(long long)b * ldA + h] = hn;
  hB[(long long)b * ldB + h] = hn;
}

// ------------------------- gate + attention (sequential dots) --------------
__global__ __launch_bounds__(256)
void gate_attn(const float* __restrict__ dg, const float* __restrict__ bg1,
               const float* __restrict__ Wg2, const float* __restrict__ bg2,
               const float* __restrict__ h2buf, const float* __restrict__ vp,
               float* __restrict__ ctx) {
  int b = blockIdx.x, tid = threadIdx.x;
  __shared__ float t1[H_], outv[H_], attn[64];
  __shared__ float gate_s;
  for (int h = tid; h < H_; h += 256)
    t1[h] = tanhf(__fadd_rn(dg[b * H_ + h], bg1[h]));
  __syncthreads();
  if (tid == 0) {
    float s = 0;
    for (int h = 0; h < H_; h++) s = fmaf(t1[h], Wg2[h], s);
    gate_s = sigf(__fadd_rn(s, bg2[0]));
  }
  __syncthreads();
  float gate = gate_s;
  for (int h = tid; h < H_; h += 256) outv[h] = __fmul_rn(h2buf[b * H_ + h], gate);
  __syncthreads();
  if (tid < KV_) {
    const float* vrow = vp + ((long long)b * KV_ + tid) * H_;
    float a = 0;
    for (int h = 0; h < H_; h++) a = fmaf(outv[h], vrow[h], a);
    attn[tid] = __fmul_rn(a, 0.03125f);   // scale = 1/sqrt(1024)
  }
  __syncthreads();
  if (tid == 0) {
    float m = -INFINITY;
    for (int k = 0; k < KV_; k++) m = fmaxf(m, attn[k]);
    float ss = 0;
    for (int k = 0; k < KV_; k++) { attn[k] = expf(attn[k] - m); ss += attn[k]; }
    for (int k = 0; k < KV_; k++) attn[k] = __fdiv_rn(attn[k], ss);
  }
  __syncthreads();
  for (int h = tid; h < H_; h += 256) {
    float acc = 0;
    for (int k = 0; k < KV_; k++) acc = fmaf(attn[k], vp[((long long)b * KV_ + k) * H_ + h], acc);
    ctx[b * H_ + h] = __fadd_rn(outv[h], acc);
  }
}

// ------------------------- init ---------------------------------------------
__global__ __launch_bounds__(256)
void init_state(const float* __restrict__ thought, const float* __restrict__ embedding,
                float* c1, float* c2, float* xcat1, float* xcat2,
                int* hist, int* histv) {
  int i = blockIdx.x * 256 + threadIdx.x;
  if (i < B_ * H_) {
    int b = i >> 10, h = i & 1023;
    c1[i] = 0.f; c2[i] = 0.f;
    float th = thought[i];
    xcat1[b * (E_ + H_) + E_ + h] = th;   // h1_0 = thought
    xcat2[b * (2 * H_) + H_ + h] = th;    // h2_0 = thought
    if (h < E_) xcat1[b * (E_ + H_) + h] = embedding[E_ + h];  // token 1
  }
  if (i < B_ * 3) { hist[i] = 0; histv[i] = 0; }
}

// ------------------------- sampling ----------------------------------------
__global__ __launch_bounds__(1024)
void sample_kernel(const float* __restrict__ dlog, const float* __restrict__ bo,
                   float* __restrict__ Lbuf, float* __restrict__ Ebuf,
                   int* __restrict__ hist, int* __restrict__ histv,
                   const float* __restrict__ embedding, float* __restrict__ xcat1,
                   int* __restrict__ outTok, int t) {
  int b = blockIdx.x, tid = threadIdx.x;
  __shared__ float redf[1024];
  __shared__ int   redi[1024];
  __shared__ unsigned long long binS[256], suf[256];
  __shared__ unsigned binC[256];
  __shared__ int jstar_s;
  __shared__ unsigned long long carry_s;
  __shared__ unsigned prefix_s;

  int hh0 = hist[b * 3 + 0], hh1 = hist[b * 3 + 1], hh2 = hist[b * 3 + 2];
  int p0 = histv[b * 3 + 0] ? hh0 : -1;
  int p1 = histv[b * 3 + 1] ? hh1 : -1;
  int p2 = histv[b * 3 + 2] ? hh2 : -1;
  const float* pa = dlog + (long long)b * V_;
  float* L = Lbuf + (long long)b * V_;
  float* E = Ebuf + (long long)b * V_;

  // pass 1: scaled logits + max
  float lm = -INFINITY;
  for (int v = tid; v < V_; v += 1024) {
    float raw = __fadd_rn(pa[v], bo[v]);
    if (v == p0 || v == p1 || v == p2) raw = __fsub_rn(raw, 2.0f);
    float l = __fdiv_rn(raw, 0.4f);
    L[v] = l;
    lm = fmaxf(lm, l);
  }
  redf[tid] = lm; __syncthreads();
  for (int off = 512; off > 0; off >>= 1) { if (tid < off) redf[tid] = fmaxf(redf[tid], redf[tid + off]); __syncthreads(); }
  float m = redf[0];
  __syncthreads();

  // pass 2: exp + sum
  float ls = 0;
  for (int v = tid; v < V_; v += 1024) { float e = expf(L[v] - m); E[v] = e; ls += e; }
  redf[tid] = ls; __syncthreads();
  for (int off = 512; off > 0; off >>= 1) { if (tid < off) redf[tid] += redf[tid + off]; __syncthreads(); }
  float Z = redf[0];
  __syncthreads();

  // radix select: K* = key of smallest kept token; kept iff mass(keys>k) <= 0.7f
  const double SC = 17592186044416.0; // 2^44
  const unsigned long long B0 =
      (unsigned long long)(0.699999988079071044921875 * 17592186044416.0); // (double)0.7f * 2^44
  if (tid == 0) { carry_s = 0ull; prefix_s = 0u; }
  __syncthreads();
  for (int pass = 0; pass < 4; pass++) {
    int shift = 24 - 8 * pass;
    unsigned maskk = (pass == 0) ? 0u : (0xFFFFFFFFu << (shift + 8));
    if (tid < 256) { binS[tid] = 0ull; binC[tid] = 0u; }
    __syncthreads();
    unsigned pref = prefix_s;
    unsigned long long carry = carry_s;
    for (int v = tid; v < V_; v += 1024) {
      unsigned key = key_of(L[v]);
      if ((key & maskk) == pref) {
        unsigned bin = (key >> shift) & 255u;
        unsigned long long S = (unsigned long long)((double)(E[v] / Z) * SC);
        atomicAdd(&binS[bin], S);
        atomicAdd(&binC[bin], 1u);
      }
    }
    __syncthreads();
    if (tid < 256) suf[tid] = binS[tid];
    __syncthreads();
    for (int off = 1; off < 256; off <<= 1) {
      unsigned long long add = 0ull;
      if (tid < 256 && tid + off < 256) add = suf[tid + off];
      __syncthreads();
      if (tid < 256) suf[tid] += add;
      __syncthreads();
    }
    if (tid == 0) jstar_s = 256;
    __syncthreads();
    if (tid < 256 && binC[tid] > 0u) {
      unsigned long long A = carry + ((tid < 255) ? suf[tid + 1] : 0ull);
      if (A <= B0) atomicMin(&jstar_s, tid);
    }
    __syncthreads();
    if (tid == 0) {
      int j = jstar_s;
      carry_s = carry + ((j < 255) ? suf[j + 1] : 0ull);
      prefix_s = pref | (((unsigned)j) << shift);
    }
    __syncthreads();
  }
  unsigned Kstar = prefix_s;

  // step key (partitionable foldlike split of key(42))
  unsigned kt0, kt1;
  tf2x32(0u, 42u, 0u, (unsigned)t, kt0, kt1);

  // gumbel argmax over kept set
  float bestv = -INFINITY; int besti = 0x7fffffff;
  for (int v = tid; v < V_; v += 1024) {
    float l = L[v];
    if (key_of(l) >= Kstar) {
      unsigned r0, r1;
      tf2x32(kt0, kt1, 0u, (unsigned)(b * V_ + v), r0, r1);
      unsigned bits = r0 ^ r1;
      float u = __uint_as_float((bits >> 9) | 0x3f800000u) - 1.0f;
      u = fmaxf(u, 1.17549435e-38f);
      float gum = -logf(-logf(u));
      float val = __fadd_rn(l, gum);
      if (val > bestv) { bestv = val; besti = v; }
    }
  }
  redf[tid] = bestv; redi[tid] = besti; __syncthreads();
  for (int off = 512; off > 0; off >>= 1) {
    if (tid < off) {
      float ov = redf[tid + off]; int oi = redi[tid + off];
      if (ov > redf[tid] || (ov == redf[tid] && oi < redi[tid])) { redf[tid] = ov; redi[tid] = oi; }
    }
    __syncthreads();
  }
  int tok = redi[0];
  if (tid == 0) {
    outTok[b * T_ + t] = tok;
    hist[b * 3 + 0] = hh1; hist[b * 3 + 1] = hh2; hist[b * 3 + 2] = tok;
    int v1 = histv[b * 3 + 1], v2 = histv[b * 3 + 2];
    histv[b * 3 + 0] = v1; histv[b * 3 + 1] = v2; histv[b * 3 + 2] = 1;
  }
  // next-step embedding gather
  for (int k = tid; k < E_; k += 1024)
    xcat1[b * (E_ + H_) + k] = embedding[(long long)tok * E_ + k];
}

// ---------------------------------------------------------------------------
extern "C" void kernel_launch(void* const* d_in, const int* in_sizes, int n_in,
                              void* d_out, int out_size, void* d_ws, size_t ws_size,
                              hipStream_t stream) {
  const float* thought   = (const float*)d_in[0];
  const float* visf      = (const float*)d_in[1];
  const float* embedding = (const float*)d_in[3];
  const float* Wih1 = (const float*)d_in[4];
  const float* Whh1 = (const float*)d_in[5];
  const float* bih1 = (const float*)d_in[6];
  const float* bhh1 = (const float*)d_in[7];
  const float* Wih2 = (const float*)d_in[8];
  const float* Whh2 = (const float*)d_in[9];
  const float* bih2 = (const float*)d_in[10];
  const float* bhh2 = (const float*)d_in[11];
  const float* Wg1  = (const float*)d_in[12];
  const float* bg1  = (const float*)d_in[13];
  const float* Wg2  = (const float*)d_in[14];
  const float* bg2  = (const float*)d_in[15];
  const float* Wo   = (const float*)d_in[16];
  const float* bo   = (const float*)d_in[17];
  const float* Wv   = (const float*)d_in[18];
  const float* bv   = (const float*)d_in[19];
  const float* ln_g = (const float*)d_in[20];
  const float* ln_b = (const float*)d_in[21];
  int* outTok = (int*)d_out;

  // workspace layout (floats)
  float* ws = (float*)d_ws;
  long long off = 0;
  float* vp    = ws + off; off += (long long)B_ * KV_ * H_;   // 3,211,264
  float* xcat1 = ws + off; off += B_ * (E_ + H_);
  float* xcat2 = ws + off; off += B_ * (2 * H_);
  float* c1    = ws + off; off += B_ * H_;
  float* c2    = ws + off; off += B_ * H_;
  float* h2buf = ws + off; off += B_ * H_;
  float* ctx   = ws + off; off += B_ * H_;
  float* dx    = ws + off; off += (long long)B_ * 4096;
  float* dh    = ws + off; off += (long long)B_ * 4096;
  float* dg    = ws + off; off += (long long)B_ * H_;
  float* dlog  = ws + off; off += (long long)B_ * V_;
  float* Lbuf  = ws + off; off += (long long)B_ * V_;
  float* Ebuf  = ws + off; off += (long long)B_ * V_;
  int* hist  = (int*)(ws + off); off += 256;   // 192 used, padded
  int* histv = (int*)(ws + off); off += 256;   // 192 used, padded

  // init recurrent state
  init_state<<<256, 256, 0, stream>>>(thought, embedding, c1, c2, xcat1, xcat2, hist, histv);

  // visual_proj: vp_pre = visf @ Wv^T (M=3136, N=1024, K=512), then LN(+bv)
  gemm_seq<<<dim3(H_ / 64, (B_ * KV_) / 64), 256, 0, stream>>>(
      visf, DV_, Wv, DV_, vp, H_, DV_);
  ln_vp<<<B_ * KV_, 256, 0, stream>>>(vp, bv, ln_g, ln_b);

  for (int t = 0; t < T_; t++) {
    // layer 1: dx = emb @ Wih1^T, dh = h1 @ Whh1^T (separate rounded dots)
    gemm_seq<<<dim3(64, 1), 256, 0, stream>>>(xcat1, E_ + H_, Wih1, E_, dx, 4096, E_);
    gemm_seq<<<dim3(64, 1), 256, 0, stream>>>(xcat1 + E_, E_ + H_, Whh1, H_, dh, 4096, H_);
    lstm_cell2<<<256, 256, 0, stream>>>(dx, dh, bih1, bhh1, c1,
                                        xcat1 + E_, E_ + H_, xcat2, 2 * H_);
    // layer 2
    gemm_seq<<<dim3(64, 1), 256, 0, stream>>>(xcat2, 2 * H_, Wih2, H_, dx, 4096, H_);
    gemm_seq<<<dim3(64, 1), 256, 0, stream>>>(xcat2 + H_, 2 * H_, Whh2, H_, dh, 4096, H_);
    lstm_cell2<<<256, 256, 0, stream>>>(dx, dh, bih2, bhh2, c2,
                                        h2buf, H_, xcat2 + H_, 2 * H_);
    // gate pre-activation: dg = h2 @ Wg1^T
    gemm_seq<<<dim3(16, 1), 256, 0, stream>>>(h2buf, H_, Wg1, H_, dg, H_, H_);
    gate_attn<<<B_, 256, 0, stream>>>(dg, bg1, Wg2, bg2, h2buf, vp, ctx);
    // logits = ctx @ Wo^T
    gemm_seq<<<dim3(V_ / 64, 1), 256, 0, stream>>>(ctx, H_, Wo, H_, dlog, V_, H_);
    sample_kernel<<<B_, 1024, 0, stream>>>(dlog, bo, Lbuf, Ebuf, hist, histv,
                                           embedding, xcat1, outTok, t);
  }
}

// Round 3
// 31896.915 us; speedup vs baseline: 2.3474x; 2.3474x over previous
//
#include <hip/hip_runtime.h>
#include <hip/hip_bf16.h>
#include <stdint.h>

// ---------------------------------------------------------------------------
// BioDecoder: 64-step LSTM decoder w/ attention, rep-penalty, temperature=0.4,
// top-p=0.7, jax.random.categorical (Threefry partitionable). All fp32.
// Association discipline: every dot = strict sequential-k single-acc fma chain.
// R2: 64x32-tile dual-GEMM (dx+dh fused per launch), float4 LDS, 4x occupancy.
// ---------------------------------------------------------------------------

#define B_   64
#define H_   1024
#define E_   512
#define DV_  512
#define KV_  49
#define V_   32000
#define T_   64

// ------------------------- Threefry-2x32-20 (JAX) --------------------------
__device__ __forceinline__ uint32_t rotl32(uint32_t x, int r) {
  return (x << r) | (x >> (32 - r));
}
__device__ __forceinline__ void tf2x32(uint32_t k0, uint32_t k1,
                                       uint32_t x0, uint32_t x1,
                                       uint32_t& o0, uint32_t& o1) {
  uint32_t ks0 = k0, ks1 = k1, ks2 = k0 ^ k1 ^ 0x1BD11BDAu;
  x0 += ks0; x1 += ks1;
#define RND_(r) { x0 += x1; x1 = rotl32(x1, r) ^ x0; }
  RND_(13) RND_(15) RND_(26) RND_(6)  x0 += ks1; x1 += ks2 + 1u;
  RND_(17) RND_(29) RND_(16) RND_(24) x0 += ks2; x1 += ks0 + 2u;
  RND_(13) RND_(15) RND_(26) RND_(6)  x0 += ks0; x1 += ks1 + 3u;
  RND_(17) RND_(29) RND_(16) RND_(24) x0 += ks1; x1 += ks2 + 4u;
  RND_(13) RND_(15) RND_(26) RND_(6)  x0 += ks2; x1 += ks0 + 5u;
#undef RND_
  o0 = x0; o1 = x1;
}

__device__ __forceinline__ unsigned key_of(float f) {
  unsigned u = __float_as_uint(f);
  return (u & 0x80000000u) ? ~u : (u | 0x80000000u);
}
__device__ __forceinline__ float sigf(float x) { return 1.0f / (1.0f + expf(-x)); }

// ------------------------- 64x32-tile sequential-k GEMM --------------------
// out[m][n] = sum_k A[m][k]*W[n][k], k ascending, one fma chain per output.
// Two descriptor sets per launch: blockIdx.x < nt0 -> set0, else set1.
// M-tile from blockIdx.y (64 rows). K must be a multiple of 32.
__global__ __launch_bounds__(256)
void gemm32(const float* __restrict__ A0, int lda0, const float* __restrict__ W0,
            int ldw0, int K0, float* __restrict__ out0, int ldo0, int nt0,
            const float* __restrict__ A1, int lda1, const float* __restrict__ W1,
            int ldw1, int K1, float* __restrict__ out1, int ldo1) {
  __shared__ __align__(16) float As[64][36];
  __shared__ __align__(16) float Ws[32][36];
  int tid = threadIdx.x;
  int bx = blockIdx.x;
  const float* A; const float* W; float* out;
  int lda, ldw, K, ldo, n0;
  if (bx < nt0) { A = A0; W = W0; out = out0; lda = lda0; ldw = ldw0; K = K0; ldo = ldo0; n0 = bx * 32; }
  else          { A = A1; W = W1; out = out1; lda = lda1; ldw = ldw1; K = K1; ldo = ldo1; n0 = (bx - nt0) * 32; }
  int m0 = blockIdx.y * 64;
  int tc = tid & 15, tr = tid >> 4;      // tc: 16 col-groups x2, tr: 16 row-groups x4
  float acc[4][2] = {};
  for (int kc = 0; kc < K; kc += 32) {
#pragma unroll
    for (int l = tid; l < 768; l += 256) {
      if (l < 512) {
        int r = l >> 3, c4 = l & 7;
        *(float4*)&As[r][c4 * 4] =
            *(const float4*)&A[(long long)(m0 + r) * lda + kc + c4 * 4];
      } else {
        int q = l - 512;
        int r = q >> 3, c4 = q & 7;
        *(float4*)&Ws[r][c4 * 4] =
            *(const float4*)&W[(long long)(n0 + r) * ldw + kc + c4 * 4];
      }
    }
    __syncthreads();
#pragma unroll
    for (int kk4 = 0; kk4 < 8; kk4++) {
      float4 a4[4], w4[2];
#pragma unroll
      for (int i = 0; i < 4; i++) a4[i] = *(const float4*)&As[tr * 4 + i][kk4 * 4];
#pragma unroll
      for (int j = 0; j < 2; j++) w4[j] = *(const float4*)&Ws[tc * 2 + j][kk4 * 4];
#pragma unroll
      for (int i = 0; i < 4; i++)
#pragma unroll
        for (int j = 0; j < 2; j++) {
          acc[i][j] = fmaf(a4[i].x, w4[j].x, acc[i][j]);
          acc[i][j] = fmaf(a4[i].y, w4[j].y, acc[i][j]);
          acc[i][j] = fmaf(a4[i].z, w4[j].z, acc[i][j]);
          acc[i][j] = fmaf(a4[i].w, w4[j].w, acc[i][j]);
        }
    }
    __syncthreads();
  }
#pragma unroll
  for (int i = 0; i < 4; i++)
#pragma unroll
    for (int j = 0; j < 2; j++)
      out[(long long)(m0 + tr * 4 + i) * ldo + n0 + tc * 2 + j] = acc[i][j];
}

// ------------------------- LayerNorm for vp --------------------------------
__global__ __launch_bounds__(256)
void ln_vp(float* __restrict__ vp, const float* __restrict__ bv,
           const float* __restrict__ g, const float* __restrict__ bt) {
  int row = blockIdx.x, tid = threadIdx.x;
  __shared__ float buf[H_];
  __shared__ float red[256];
  float* p = vp + (long long)row * H_;
  for (int h = tid; h < H_; h += 256) buf[h] = __fadd_rn(p[h], bv[h]);
  __syncthreads();
  float s = 0;
  for (int h = tid; h < H_; h += 256) s += buf[h];
  red[tid] = s; __syncthreads();
  for (int off = 128; off > 0; off >>= 1) { if (tid < off) red[tid] += red[tid + off]; __syncthreads(); }
  float mu = red[0] / (float)H_;
  __syncthreads();
  float vs = 0;
  for (int h = tid; h < H_; h += 256) { float d = buf[h] - mu; vs += d * d; }
  red[tid] = vs; __syncthreads();
  for (int off = 128; off > 0; off >>= 1) { if (tid < off) red[tid] += red[tid + off]; __syncthreads(); }
  float var = red[0] / (float)H_;
  float sq = sqrtf(var + 1e-5f);
  for (int h = tid; h < H_; h += 256) {
    float nrm = __fdiv_rn(__fsub_rn(buf[h], mu), sq);
    p[h] = __fadd_rn(__fmul_rn(nrm, g[h]), bt[h]);
  }
}

// ------------------------- LSTM cell ---------------------------------------
// z = ((dx + dh) + bih) + bhh  (left-assoc, matches ref); gate order i,f,g,o.
__global__ __launch_bounds__(256)
void lstm_cell2(const float* __restrict__ dx, const float* __restrict__ dh,
                const float* __restrict__ bih, const float* __restrict__ bhh,
                float* __restrict__ c,
                float* __restrict__ hA, int ldA, float* __restrict__ hB, int ldB) {
  int idx = blockIdx.x * 256 + threadIdx.x;      // 64*1024
  int b = idx >> 10, h = idx & 1023;
  float z[4];
#pragma unroll
  for (int g = 0; g < 4; g++) {
    int j = g * 1024 + h;
    float s = __fadd_rn(dx[b * 4096 + j], dh[b * 4096 + j]);
    s = __fadd_rn(s, bih[j]);
    s = __fadd_rn(s, bhh[j]);
    z[g] = s;
  }
  float fc = __fmul_rn(sigf(z[1]), c[idx]);
  float ig = __fmul_rn(sigf(z[0]), tanhf(z[2]));
  float cn = __fadd_rn(fc, ig);
  float hn = __fmul_rn(sigf(z[3]), tanhf(cn));
  c[idx] = cn;
  hA[(long long)b * ldA + h] = hn;
  hB[(long long)b * ldB + h] = hn;
}

// ------------------------- gate + attention (sequential dots) --------------
__global__ __launch_bounds__(256)
void gate_attn(const float* __restrict__ dg, const float* __restrict__ bg1,
               const float* __restrict__ Wg2, const float* __restrict__ bg2,
               const float* __restrict__ h2buf, const float* __restrict__ vp,
               float* __restrict__ ctx) {
  int b = blockIdx.x, tid = threadIdx.x;
  __shared__ float t1[H_], outv[H_], attn[64];
  __shared__ float gate_s;
  for (int h = tid; h < H_; h += 256)
    t1[h] = tanhf(__fadd_rn(dg[b * H_ + h], bg1[h]));
  __syncthreads();
  if (tid == 0) {
    float s = 0;
    for (int h = 0; h < H_; h++) s = fmaf(t1[h], Wg2[h], s);
    gate_s = sigf(__fadd_rn(s, bg2[0]));
  }
  __syncthreads();
  float gate = gate_s;
  for (int h = tid; h < H_; h += 256) outv[h] = __fmul_rn(h2buf[b * H_ + h], gate);
  __syncthreads();
  if (tid < KV_) {
    const float* vrow = vp + ((long long)b * KV_ + tid) * H_;
    float a = 0;
    for (int h = 0; h < H_; h++) a = fmaf(outv[h], vrow[h], a);
    attn[tid] = __fmul_rn(a, 0.03125f);   // scale = 1/sqrt(1024)
  }
  __syncthreads();
  if (tid == 0) {
    float m = -INFINITY;
    for (int k = 0; k < KV_; k++) m = fmaxf(m, attn[k]);
    float ss = 0;
    for (int k = 0; k < KV_; k++) { attn[k] = expf(attn[k] - m); ss += attn[k]; }
    for (int k = 0; k < KV_; k++) attn[k] = __fdiv_rn(attn[k], ss);
  }
  __syncthreads();
  for (int h = tid; h < H_; h += 256) {
    float acc = 0;
    for (int k = 0; k < KV_; k++) acc = fmaf(attn[k], vp[((long long)b * KV_ + k) * H_ + h], acc);
    ctx[b * H_ + h] = __fadd_rn(outv[h], acc);
  }
}

// ------------------------- init ---------------------------------------------
__global__ __launch_bounds__(256)
void init_state(const float* __restrict__ thought, const float* __restrict__ embedding,
                float* c1, float* c2, float* xcat1, float* xcat2,
                int* hist, int* histv) {
  int i = blockIdx.x * 256 + threadIdx.x;
  if (i < B_ * H_) {
    int b = i >> 10, h = i & 1023;
    c1[i] = 0.f; c2[i] = 0.f;
    float th = thought[i];
    xcat1[b * (E_ + H_) + E_ + h] = th;   // h1_0 = thought
    xcat2[b * (2 * H_) + H_ + h] = th;    // h2_0 = thought
    if (h < E_) xcat1[b * (E_ + H_) + h] = embedding[E_ + h];  // token 1
  }
  if (i < B_ * 3) { hist[i] = 0; histv[i] = 0; }
}

// ------------------------- sampling ----------------------------------------
__global__ __launch_bounds__(1024)
void sample_kernel(const float* __restrict__ dlog, const float* __restrict__ bo,
                   float* __restrict__ Lbuf, float* __restrict__ Ebuf,
                   int* __restrict__ hist, int* __restrict__ histv,
                   const float* __restrict__ embedding, float* __restrict__ xcat1,
                   int* __restrict__ outTok, int t) {
  int b = blockIdx.x, tid = threadIdx.x;
  __shared__ float redf[1024];
  __shared__ int   redi[1024];
  __shared__ unsigned long long binS[256], suf[256];
  __shared__ unsigned binC[256];
  __shared__ int jstar_s;
  __shared__ unsigned long long carry_s;
  __shared__ unsigned prefix_s;

  int hh0 = hist[b * 3 + 0], hh1 = hist[b * 3 + 1], hh2 = hist[b * 3 + 2];
  int p0 = histv[b * 3 + 0] ? hh0 : -1;
  int p1 = histv[b * 3 + 1] ? hh1 : -1;
  int p2 = histv[b * 3 + 2] ? hh2 : -1;
  const float* pa = dlog + (long long)b * V_;
  float* L = Lbuf + (long long)b * V_;
  float* E = Ebuf + (long long)b * V_;

  // pass 1: scaled logits + max
  float lm = -INFINITY;
  for (int v = tid; v < V_; v += 1024) {
    float raw = __fadd_rn(pa[v], bo[v]);
    if (v == p0 || v == p1 || v == p2) raw = __fsub_rn(raw, 2.0f);
    float l = __fdiv_rn(raw, 0.4f);
    L[v] = l;
    lm = fmaxf(lm, l);
  }
  redf[tid] = lm; __syncthreads();
  for (int off = 512; off > 0; off >>= 1) { if (tid < off) redf[tid] = fmaxf(redf[tid], redf[tid + off]); __syncthreads(); }
  float m = redf[0];
  __syncthreads();

  // pass 2: exp + sum
  float ls = 0;
  for (int v = tid; v < V_; v += 1024) { float e = expf(L[v] - m); E[v] = e; ls += e; }
  redf[tid] = ls; __syncthreads();
  for (int off = 512; off > 0; off >>= 1) { if (tid < off) redf[tid] += redf[tid + off]; __syncthreads(); }
  float Z = redf[0];
  __syncthreads();

  // radix select: K* = key of smallest kept token; kept iff mass(keys>k) <= 0.7f
  const double SC = 17592186044416.0; // 2^44
  const unsigned long long B0 =
      (unsigned long long)(0.699999988079071044921875 * 17592186044416.0); // (double)0.7f * 2^44
  if (tid == 0) { carry_s = 0ull; prefix_s = 0u; }
  __syncthreads();
  for (int pass = 0; pass < 4; pass++) {
    int shift = 24 - 8 * pass;
    unsigned maskk = (pass == 0) ? 0u : (0xFFFFFFFFu << (shift + 8));
    if (tid < 256) { binS[tid] = 0ull; binC[tid] = 0u; }
    __syncthreads();
    unsigned pref = prefix_s;
    unsigned long long carry = carry_s;
    for (int v = tid; v < V_; v += 1024) {
      unsigned key = key_of(L[v]);
      if ((key & maskk) == pref) {
        unsigned bin = (key >> shift) & 255u;
        unsigned long long S = (unsigned long long)((double)(E[v] / Z) * SC);
        atomicAdd(&binS[bin], S);
        atomicAdd(&binC[bin], 1u);
      }
    }
    __syncthreads();
    if (tid < 256) suf[tid] = binS[tid];
    __syncthreads();
    for (int off = 1; off < 256; off <<= 1) {
      unsigned long long add = 0ull;
      if (tid < 256 && tid + off < 256) add = suf[tid + off];
      __syncthreads();
      if (tid < 256) suf[tid] += add;
      __syncthreads();
    }
    if (tid == 0) jstar_s = 256;
    __syncthreads();
    if (tid < 256 && binC[tid] > 0u) {
      unsigned long long A = carry + ((tid < 255) ? suf[tid + 1] : 0ull);
      if (A <= B0) atomicMin(&jstar_s, tid);
    }
    __syncthreads();
    if (tid == 0) {
      int j = jstar_s;
      carry_s = carry + ((j < 255) ? suf[j + 1] : 0ull);
      prefix_s = pref | (((unsigned)j) << shift);
    }
    __syncthreads();
  }
  unsigned Kstar = prefix_s;

  // step key (partitionable foldlike split of key(42))
  unsigned kt0, kt1;
  tf2x32(0u, 42u, 0u, (unsigned)t, kt0, kt1);

  // gumbel argmax over kept set
  float bestv = -INFINITY; int besti = 0x7fffffff;
  for (int v = tid; v < V_; v += 1024) {
    float l = L[v];
    if (key_of(l) >= Kstar) {
      unsigned r0, r1;
      tf2x32(kt0, kt1, 0u, (unsigned)(b * V_ + v), r0, r1);
      unsigned bits = r0 ^ r1;
      float u = __uint_as_float((bits >> 9) | 0x3f800000u) - 1.0f;
      u = fmaxf(u, 1.17549435e-38f);
      float gum = -logf(-logf(u));
      float val = __fadd_rn(l, gum);
      if (val > bestv) { bestv = val; besti = v; }
    }
  }
  redf[tid] = bestv; redi[tid] = besti; __syncthreads();
  for (int off = 512; off > 0; off >>= 1) {
    if (tid < off) {
      float ov = redf[tid + off]; int oi = redi[tid + off];
      if (ov > redf[tid] || (ov == redf[tid] && oi < redi[tid])) { redf[tid] = ov; redi[tid] = oi; }
    }
    __syncthreads();
  }
  int tok = redi[0];
  if (tid == 0) {
    outTok[b * T_ + t] = tok;
    hist[b * 3 + 0] = hh1; hist[b * 3 + 1] = hh2; hist[b * 3 + 2] = tok;
    int v1 = histv[b * 3 + 1], v2 = histv[b * 3 + 2];
    histv[b * 3 + 0] = v1; histv[b * 3 + 1] = v2; histv[b * 3 + 2] = 1;
  }
  // next-step embedding gather
  for (int k = tid; k < E_; k += 1024)
    xcat1[b * (E_ + H_) + k] = embedding[(long long)tok * E_ + k];
}

// ---------------------------------------------------------------------------
extern "C" void kernel_launch(void* const* d_in, const int* in_sizes, int n_in,
                              void* d_out, int out_size, void* d_ws, size_t ws_size,
                              hipStream_t stream) {
  const float* thought   = (const float*)d_in[0];
  const float* visf      = (const float*)d_in[1];
  const float* embedding = (const float*)d_in[3];
  const float* Wih1 = (const float*)d_in[4];
  const float* Whh1 = (const float*)d_in[5];
  const float* bih1 = (const float*)d_in[6];
  const float* bhh1 = (const float*)d_in[7];
  const float* Wih2 = (const float*)d_in[8];
  const float* Whh2 = (const float*)d_in[9];
  const float* bih2 = (const float*)d_in[10];
  const float* bhh2 = (const float*)d_in[11];
  const float* Wg1  = (const float*)d_in[12];
  const float* bg1  = (const float*)d_in[13];
  const float* Wg2  = (const float*)d_in[14];
  const float* bg2  = (const float*)d_in[15];
  const float* Wo   = (const float*)d_in[16];
  const float* bo   = (const float*)d_in[17];
  const float* Wv   = (const float*)d_in[18];
  const float* bv   = (const float*)d_in[19];
  const float* ln_g = (const float*)d_in[20];
  const float* ln_b = (const float*)d_in[21];
  int* outTok = (int*)d_out;

  // workspace layout (floats)
  float* ws = (float*)d_ws;
  long long off = 0;
  float* vp    = ws + off; off += (long long)B_ * KV_ * H_;   // 3,211,264
  float* xcat1 = ws + off; off += B_ * (E_ + H_);
  float* xcat2 = ws + off; off += B_ * (2 * H_);
  float* c1    = ws + off; off += B_ * H_;
  float* c2    = ws + off; off += B_ * H_;
  float* h2buf = ws + off; off += B_ * H_;
  float* ctx   = ws + off; off += B_ * H_;
  float* dx    = ws + off; off += (long long)B_ * 4096;
  float* dh    = ws + off; off += (long long)B_ * 4096;
  float* dg    = ws + off; off += (long long)B_ * H_;
  float* dlog  = ws + off; off += (long long)B_ * V_;
  float* Lbuf  = ws + off; off += (long long)B_ * V_;
  float* Ebuf  = ws + off; off += (long long)B_ * V_;
  int* hist  = (int*)(ws + off); off += 256;   // 192 used, padded
  int* histv = (int*)(ws + off); off += 256;   // 192 used, padded

  // init recurrent state
  init_state<<<256, 256, 0, stream>>>(thought, embedding, c1, c2, xcat1, xcat2, hist, histv);

  // visual_proj: vp_pre = visf @ Wv^T (M=3136, N=1024, K=512), then LN(+bv)
  gemm32<<<dim3(32, KV_), 256, 0, stream>>>(
      visf, DV_, Wv, DV_, DV_, vp, H_, 32,
      visf, DV_, Wv, DV_, DV_, vp, H_);
  ln_vp<<<B_ * KV_, 256, 0, stream>>>(vp, bv, ln_g, ln_b);

  for (int t = 0; t < T_; t++) {
    // layer 1: dx = emb @ Wih1^T (K=512), dh = h1 @ Whh1^T (K=1024) — one launch
    gemm32<<<dim3(256, 1), 256, 0, stream>>>(
        xcat1, E_ + H_, Wih1, E_, E_, dx, 4096, 128,
        xcat1 + E_, E_ + H_, Whh1, H_, H_, dh, 4096);
    lstm_cell2<<<256, 256, 0, stream>>>(dx, dh, bih1, bhh1, c1,
                                        xcat1 + E_, E_ + H_, xcat2, 2 * H_);
    // layer 2: dx = h1 @ Wih2^T, dh = h2 @ Whh2^T — one launch
    gemm32<<<dim3(256, 1), 256, 0, stream>>>(
        xcat2, 2 * H_, Wih2, H_, H_, dx, 4096, 128,
        xcat2 + H_, 2 * H_, Whh2, H_, H_, dh, 4096);
    lstm_cell2<<<256, 256, 0, stream>>>(dx, dh, bih2, bhh2, c2,
                                        h2buf, H_, xcat2 + H_, 2 * H_);
    // gate pre-activation: dg = h2 @ Wg1^T (N=1024 -> 32 blocks)
    gemm32<<<dim3(32, 1), 256, 0, stream>>>(
        h2buf, H_, Wg1, H_, H_, dg, H_, 32,
        h2buf, H_, Wg1, H_, H_, dg, H_);
    gate_attn<<<B_, 256, 0, stream>>>(dg, bg1, Wg2, bg2, h2buf, vp, ctx);
    // logits = ctx @ Wo^T (N=32000 -> 1000 blocks)
    gemm32<<<dim3(1000, 1), 256, 0, stream>>>(
        ctx, H_, Wo, H_, H_, dlog, V_, 1000,
        ctx, H_, Wo, H_, H_, dlog, V_);
    sample_kernel<<<B_, 1024, 0, stream>>>(dlog, bo, Lbuf, Ebuf, hist, histv,
                                           embedding, xcat1, outTok, t);
  }
}